// Round 2
// baseline (330.427 us; speedup 1.0000x reference)
//
#include <hip/hip_runtime.h>

// Problem constants (match reference)
#define NUM_P      16
#define STEP       4
#define NUM_BLOCKS 256   // blocks per permutation (DIM / STEP)
#define DIM        1024
#define BATCH      4096
#define ROWS_PER_BLOCK 16   // batch rows staged per block (64 KB LDS)

// Kernel A: extract the block permutation from the dense T matrices.
// T[p, 4r, 4c] == 1.0 exactly when permutation p maps block-row r to
// block-col c. The eye-block's first-row 1 sits at lane 0 of the
// 16B-aligned float4 at T[p][4r][4c]; consecutive c-threads read
// consecutive float4s -> fully coalesced.
__global__ __launch_bounds__(256) void extract_perm_kernel(
    const float4* __restrict__ T4, int* __restrict__ perm) {
    int idx = blockIdx.x * blockDim.x + threadIdx.x;  // p*65536 + r*256 + c
    int c = idx & (NUM_BLOCKS - 1);
    int r = (idx >> 8) & (NUM_BLOCKS - 1);
    int p = idx >> 16;
    size_t off4 = (size_t)p * (DIM * DIM / 4) + (size_t)(STEP * r) * (DIM / 4) + c;
    float4 v = T4[off4];
    if (v.x != 0.0f) {
        perm[p * NUM_BLOCKS + r] = c;
    }
}

// Kernel B: block <-> (output group i, chunk of 16 batch rows), i is the
// SLOW grid index. Rationale (round-0/1 post-mortem):
//  - round 0: perfect streaming writes, scattered 16B reads  -> ~150us
//  - round 1: perfect reads, 16 interleaved 4KB write streams -> ~150us
//  Fixing one side while breaking the other is a wash. This version
//  streams BOTH: coalesced row loads into LDS, then one contiguous
//  64 KB write region per block, extended by consecutive blocks.
//  x is re-read once per i (256 MB total) but x = 16 MiB lives in the
//  256 MiB Infinity Cache, so HBM fetch stays ~16 MB.
//  Since i is block-uniform, each thread's source index is ONE register:
//  c = perm[indices[i]][tid] -- no perm staging in LDS at all.
__global__ __launch_bounds__(256) void gather_kernel(
    const float4* __restrict__ x4,
    const int* __restrict__ perm,
    const int* __restrict__ indices,
    float4* __restrict__ out4) {
    __shared__ float4 rows[ROWS_PER_BLOCK][NUM_BLOCKS];  // 64 KB
    const int tid   = threadIdx.x;
    const int i     = blockIdx.x >> 8;          // 0..15  (slow index)
    const int chunk = blockIdx.x & 255;         // 0..255
    const int b0    = chunk * ROWS_PER_BLOCK;

    const int q = indices[i];                   // block-uniform scalar load
    const int c = perm[q * NUM_BLOCKS + tid];   // one coalesced 1 KB load (L2-hot)

    // Stage 16 x-rows, fully coalesced (each row: 256 threads x 16 B).
#pragma unroll
    for (int r = 0; r < ROWS_PER_BLOCK; ++r) {
        rows[r][tid] = x4[(size_t)(b0 + r) * NUM_BLOCKS + tid];
    }
    __syncthreads();

    // 16 contiguous 4 KB stores forming one 64 KB contiguous region.
    // LDS gather rows[r][c]: ~8-way bank conflict average, off the
    // critical path (write stream is the limiter).
#pragma unroll
    for (int r = 0; r < ROWS_PER_BLOCK; ++r) {
        out4[((size_t)i * BATCH + b0 + r) * NUM_BLOCKS + tid] = rows[r][c];
    }
}

extern "C" void kernel_launch(void* const* d_in, const int* in_sizes, int n_in,
                              void* d_out, int out_size, void* d_ws, size_t ws_size,
                              hipStream_t stream) {
    const float* x       = (const float*)d_in[0];   // [BATCH, DIM] fp32
    const float* T       = (const float*)d_in[1];   // [NUM_P, DIM, DIM] fp32
    const int*   indices = (const int*)d_in[2];     // [NUM_P] int32
    float* out = (float*)d_out;                     // [NUM_P*BATCH, DIM] fp32

    int* perm = (int*)d_ws;                         // NUM_P * NUM_BLOCKS ints (16 KiB)

    // Kernel A: 16*256*256 threads, coalesced float4 reads (16 MiB of T).
    {
        int total = NUM_P * NUM_BLOCKS * NUM_BLOCKS;
        dim3 block(256);
        dim3 grid(total / 256);
        extract_perm_kernel<<<grid, block, 0, stream>>>((const float4*)T, perm);
    }

    // Kernel B: 16 groups x 256 chunks = 4096 blocks, 256 threads.
    // 64 KB LDS -> 2 blocks/CU resident; streaming kernel, enough MLP
    // (16 independent float4 loads in flight per thread).
    {
        dim3 block(256);
        dim3 grid(NUM_P * (BATCH / ROWS_PER_BLOCK));
        gather_kernel<<<grid, block, 0, stream>>>(
            (const float4*)x, perm, indices, (float4*)out);
    }
    (void)in_sizes; (void)n_in; (void)out_size; (void)ws_size;
}

// Round 3
// 313.311 us; speedup vs baseline: 1.0546x; 1.0546x over previous
//
#include <hip/hip_runtime.h>

// Problem constants (match reference)
#define NUM_P      16
#define STEP       4
#define NUM_BLOCKS 256   // blocks per permutation (DIM / STEP)
#define DIM        1024
#define BATCH      4096
#define ROWS_PER_THREAD 4   // batch rows handled per thread in kernel B

// Native clang vector type so __builtin_nontemporal_store lowers to
// global_store_dwordx4 with the nt flag (HIP's float4 is a class and
// doesn't qualify).
typedef float f32x4 __attribute__((ext_vector_type(4)));

// Kernel A: extract the block permutation from the dense T matrices.
// T[p, 4r, 4c] == 1.0 exactly when permutation p maps block-row r to
// block-col c. The eye-block's first-row 1 sits at lane 0 of the
// 16B-aligned float4 at T[p][4r][4c]; consecutive c-threads read
// consecutive float4s -> fully coalesced (16 MiB total, ~3 us).
__global__ __launch_bounds__(256) void extract_perm_kernel(
    const f32x4* __restrict__ T4, int* __restrict__ perm) {
    int idx = blockIdx.x * blockDim.x + threadIdx.x;  // p*65536 + r*256 + c
    int c = idx & (NUM_BLOCKS - 1);
    int r = (idx >> 8) & (NUM_BLOCKS - 1);
    int p = idx >> 16;
    size_t off4 = (size_t)p * (DIM * DIM / 4) + (size_t)(STEP * r) * (DIM / 4) + c;
    f32x4 v = T4[off4];
    if (v.x != 0.0f) {
        perm[p * NUM_BLOCKS + r] = c;
    }
}

// Kernel B: back to the round-0 structure — it was empirically the best
// (311.7 us vs 323.6 / 330.4 for the LDS-staged variants). Post-mortem
// showed its reads have NO line-granularity amplification: each (i,b)
// block consumes every 64B line of row b fully (permuted order within a
// 4KB region), so reads are L2/L3-absorbed and the kernel is a pure
// write-stream + cached gather. The LDS/barrier machinery of rounds 1-2
// only added overhead.
//
// Improvements over round 0:
//  - each thread handles ROWS_PER_THREAD=4 batch rows at the same (i,j):
//    ONE perm lookup serves 4 load/store pairs, and the 4 independent
//    x-loads give MLP for latency hiding (loads hit L2/L3: x re-read
//    16x but 16 MiB => Infinity-Cache resident).
//  - nontemporal stores on the 256 MiB output stream so it doesn't
//    evict the L3-resident x / perm working set.
//  - writes remain grid-linear: consecutive blocks extend one contiguous
//    stream, the exact pattern the harness fill sustains at 6.3 TB/s.
__global__ __launch_bounds__(256) void gather_kernel(
    const f32x4* __restrict__ x4,
    const int* __restrict__ perm,
    const int* __restrict__ indices,
    f32x4* __restrict__ out4) {
    const int tid = threadIdx.x;                  // j: float4 column 0..255
    const int i   = blockIdx.x >> 10;             // output group 0..15 (slow)
    const int bg  = blockIdx.x & 1023;            // row-group within batch
    const int b0  = bg * ROWS_PER_THREAD;

    const int q = indices[i];                     // block-uniform (L2 broadcast)
    const int c = perm[q * NUM_BLOCKS + tid];     // coalesced 1 KB, L2-hot

    // 4 independent gather loads (L3-resident after first i-pass).
    f32x4 v0 = x4[(size_t)(b0 + 0) * NUM_BLOCKS + c];
    f32x4 v1 = x4[(size_t)(b0 + 1) * NUM_BLOCKS + c];
    f32x4 v2 = x4[(size_t)(b0 + 2) * NUM_BLOCKS + c];
    f32x4 v3 = x4[(size_t)(b0 + 3) * NUM_BLOCKS + c];

    f32x4* o = &out4[((size_t)i * BATCH + b0) * NUM_BLOCKS + tid];
    __builtin_nontemporal_store(v0, o + 0 * NUM_BLOCKS);
    __builtin_nontemporal_store(v1, o + 1 * NUM_BLOCKS);
    __builtin_nontemporal_store(v2, o + 2 * NUM_BLOCKS);
    __builtin_nontemporal_store(v3, o + 3 * NUM_BLOCKS);
}

extern "C" void kernel_launch(void* const* d_in, const int* in_sizes, int n_in,
                              void* d_out, int out_size, void* d_ws, size_t ws_size,
                              hipStream_t stream) {
    const float* x       = (const float*)d_in[0];   // [BATCH, DIM] fp32
    const float* T       = (const float*)d_in[1];   // [NUM_P, DIM, DIM] fp32
    const int*   indices = (const int*)d_in[2];     // [NUM_P] int32
    float* out = (float*)d_out;                     // [NUM_P*BATCH, DIM] fp32

    int* perm = (int*)d_ws;                         // NUM_P * NUM_BLOCKS ints (16 KiB)

    // Kernel A: 16*256*256 threads, coalesced float4 reads (16 MiB of T).
    {
        int total = NUM_P * NUM_BLOCKS * NUM_BLOCKS;
        dim3 block(256);
        dim3 grid(total / 256);
        extract_perm_kernel<<<grid, block, 0, stream>>>((const f32x4*)T, perm);
    }

    // Kernel B: 16 groups x 1024 row-groups = 16384 blocks, 256 threads,
    // no LDS, no barrier, minimal VGPR -> full occupancy.
    {
        dim3 block(256);
        dim3 grid(NUM_P * (BATCH / ROWS_PER_THREAD));
        gather_kernel<<<grid, block, 0, stream>>>(
            (const f32x4*)x, perm, indices, (f32x4*)out);
    }
    (void)in_sizes; (void)n_in; (void)out_size; (void)ws_size;
}